// Round 1
// baseline (5720.758 us; speedup 1.0000x reference)
//
#include <hip/hip_runtime.h>
#include <math.h>

#define BLK 128

static constexpr float SELU_SCALE = 1.0507009873554805f;
static constexpr float SELU_ALPHA = 1.6732632423543772f;

__device__ __forceinline__ float selu_f(float x) {
    return x > 0.0f ? SELU_SCALE * x : (SELU_SCALE * SELU_ALPHA) * (expf(x) - 1.0f);
}

__device__ __forceinline__ void fmac64(float (&h)[64], float x, const float* __restrict__ w) {
    #pragma unroll
    for (int j = 0; j < 64; ++j) h[j] = fmaf(x, w[j], h[j]);
}

__device__ __forceinline__ void fmac32(float (&o)[32], float x, const float* __restrict__ w) {
    #pragma unroll
    for (int j = 0; j < 32; ++j) o[j] = fmaf(x, w[j], o[j]);
}

// accumulate a 32-wide input chunk (per-lane pointer xp) into h[64]; w is the [32,64] block
__device__ __forceinline__ void chunk32_64(float (&h)[64], const float* __restrict__ xp,
                                           const float* __restrict__ w) {
    for (int k = 0; k < 32; k += 4) {
        const float4 xv = *reinterpret_cast<const float4*>(xp + k);
        fmac64(h, xv.x, w + (k + 0) * 64);
        fmac64(h, xv.y, w + (k + 1) * 64);
        fmac64(h, xv.z, w + (k + 2) * 64);
        fmac64(h, xv.w, w + (k + 3) * 64);
    }
}

__global__ __launch_bounds__(BLK) void phi_e_kernel(
    const float* __restrict__ bonds, const int* __restrict__ ba1, const int* __restrict__ ba2,
    const float* __restrict__ atoms, const float* __restrict__ state,
    const float* __restrict__ w1, const float* __restrict__ b1,
    const float* __restrict__ w2, const float* __restrict__ b2,
    const float* __restrict__ w3, const float* __restrict__ b3,
    float* __restrict__ out, float* __restrict__ b2a, int* __restrict__ cnt,
    float* __restrict__ bsum, int nb)
{
    __shared__ float hbuf[64][BLK];   // per-thread column: no cross-thread sharing, no barriers
    const int tid = threadIdx.x;
    float ssum[32];
    #pragma unroll
    for (int j = 0; j < 32; ++j) ssum[j] = 0.0f;

    for (int e = blockIdx.x * BLK + tid; e < nb; e += gridDim.x * BLK) {
        const int i1 = ba1[e];
        const int i2 = ba2[e];

        float h[64];
        #pragma unroll
        for (int j = 0; j < 64; ++j) h[j] = b1[j];
        chunk32_64(h, atoms + (size_t)i1 * 32, w1);             // a1
        chunk32_64(h, atoms + (size_t)i2 * 32, w1 + 32 * 64);   // a2
        chunk32_64(h, bonds + (size_t)e * 32,  w1 + 64 * 64);   // bond
        chunk32_64(h, state,                   w1 + 96 * 64);   // state (uniform -> s_load)
        #pragma unroll
        for (int j = 0; j < 64; ++j) hbuf[j][tid] = selu_f(h[j]);

        // layer 2: 64 -> 64
        #pragma unroll
        for (int j = 0; j < 64; ++j) h[j] = b2[j];
        for (int k = 0; k < 64; k += 4) {
            const float x0 = hbuf[k + 0][tid], x1 = hbuf[k + 1][tid];
            const float x2 = hbuf[k + 2][tid], x3 = hbuf[k + 3][tid];
            fmac64(h, x0, w2 + (k + 0) * 64);
            fmac64(h, x1, w2 + (k + 1) * 64);
            fmac64(h, x2, w2 + (k + 2) * 64);
            fmac64(h, x3, w2 + (k + 3) * 64);
        }
        #pragma unroll
        for (int j = 0; j < 64; ++j) hbuf[j][tid] = selu_f(h[j]);

        // layer 3: 64 -> 32
        float o[32];
        #pragma unroll
        for (int j = 0; j < 32; ++j) o[j] = b3[j];
        for (int k = 0; k < 64; k += 4) {
            const float x0 = hbuf[k + 0][tid], x1 = hbuf[k + 1][tid];
            const float x2 = hbuf[k + 2][tid], x3 = hbuf[k + 3][tid];
            fmac32(o, x0, w3 + (k + 0) * 32);
            fmac32(o, x1, w3 + (k + 1) * 32);
            fmac32(o, x2, w3 + (k + 2) * 32);
            fmac32(o, x3, w3 + (k + 3) * 32);
        }
        #pragma unroll
        for (int j = 0; j < 32; ++j) o[j] = selu_f(o[j]);

        float* __restrict__ op = out + (size_t)e * 32;
        #pragma unroll
        for (int j = 0; j < 32; j += 4)
            *reinterpret_cast<float4*>(op + j) = make_float4(o[j], o[j+1], o[j+2], o[j+3]);

        #pragma unroll
        for (int j = 0; j < 32; ++j) ssum[j] += o[j];

        float* __restrict__ dst = b2a + (size_t)i1 * 32;
        #pragma unroll
        for (int j = 0; j < 32; ++j) atomicAdd(dst + j, o[j]);
        atomicAdd(cnt + i1, 1);
    }

    // wave-level reduce of the per-thread feature sums, one atomic per wave per feature
    #pragma unroll
    for (int j = 0; j < 32; ++j) {
        float v = ssum[j];
        #pragma unroll
        for (int off = 32; off > 0; off >>= 1) v += __shfl_down(v, off);
        if ((tid & 63) == 0) atomicAdd(bsum + j, v);
    }
}

__global__ __launch_bounds__(BLK) void phi_v_kernel(
    const float* __restrict__ atoms, const float* __restrict__ state,
    const float* __restrict__ b2a, const int* __restrict__ cnt,
    const float* __restrict__ w1, const float* __restrict__ b1,
    const float* __restrict__ w2, const float* __restrict__ b2,
    const float* __restrict__ w3, const float* __restrict__ b3,
    float* __restrict__ out, float* __restrict__ asum, int na)
{
    __shared__ float hbuf[64][BLK];
    const int tid = threadIdx.x;
    float ssum[32];
    #pragma unroll
    for (int j = 0; j < 32; ++j) ssum[j] = 0.0f;

    for (int a = blockIdx.x * BLK + tid; a < na; a += gridDim.x * BLK) {
        const float cntf = (float)cnt[a];

        float h[64];
        #pragma unroll
        for (int j = 0; j < 64; ++j) h[j] = b1[j];
        // chunk 0: b2a / cnt
        {
            const float* __restrict__ xp = b2a + (size_t)a * 32;
            for (int k = 0; k < 32; k += 4) {
                float4 xv = *reinterpret_cast<const float4*>(xp + k);
                xv.x = xv.x / cntf; xv.y = xv.y / cntf; xv.z = xv.z / cntf; xv.w = xv.w / cntf;
                fmac64(h, xv.x, w1 + (k + 0) * 64);
                fmac64(h, xv.y, w1 + (k + 1) * 64);
                fmac64(h, xv.z, w1 + (k + 2) * 64);
                fmac64(h, xv.w, w1 + (k + 3) * 64);
            }
        }
        chunk32_64(h, atoms + (size_t)a * 32, w1 + 32 * 64);
        chunk32_64(h, state,                  w1 + 64 * 64);
        #pragma unroll
        for (int j = 0; j < 64; ++j) hbuf[j][tid] = selu_f(h[j]);

        #pragma unroll
        for (int j = 0; j < 64; ++j) h[j] = b2[j];
        for (int k = 0; k < 64; k += 4) {
            const float x0 = hbuf[k + 0][tid], x1 = hbuf[k + 1][tid];
            const float x2 = hbuf[k + 2][tid], x3 = hbuf[k + 3][tid];
            fmac64(h, x0, w2 + (k + 0) * 64);
            fmac64(h, x1, w2 + (k + 1) * 64);
            fmac64(h, x2, w2 + (k + 2) * 64);
            fmac64(h, x3, w2 + (k + 3) * 64);
        }
        #pragma unroll
        for (int j = 0; j < 64; ++j) hbuf[j][tid] = selu_f(h[j]);

        float o[32];
        #pragma unroll
        for (int j = 0; j < 32; ++j) o[j] = b3[j];
        for (int k = 0; k < 64; k += 4) {
            const float x0 = hbuf[k + 0][tid], x1 = hbuf[k + 1][tid];
            const float x2 = hbuf[k + 2][tid], x3 = hbuf[k + 3][tid];
            fmac32(o, x0, w3 + (k + 0) * 32);
            fmac32(o, x1, w3 + (k + 1) * 32);
            fmac32(o, x2, w3 + (k + 2) * 32);
            fmac32(o, x3, w3 + (k + 3) * 32);
        }
        #pragma unroll
        for (int j = 0; j < 32; ++j) o[j] = selu_f(o[j]);

        float* __restrict__ op = out + (size_t)a * 32;
        #pragma unroll
        for (int j = 0; j < 32; j += 4)
            *reinterpret_cast<float4*>(op + j) = make_float4(o[j], o[j+1], o[j+2], o[j+3]);

        #pragma unroll
        for (int j = 0; j < 32; ++j) ssum[j] += o[j];
    }

    #pragma unroll
    for (int j = 0; j < 32; ++j) {
        float v = ssum[j];
        #pragma unroll
        for (int off = 32; off > 0; off >>= 1) v += __shfl_down(v, off);
        if ((tid & 63) == 0) atomicAdd(asum + j, v);
    }
}

__global__ __launch_bounds__(128) void phi_u_kernel(
    const float* __restrict__ bsum, const float* __restrict__ asum,
    const float* __restrict__ state,
    const float* __restrict__ w1, const float* __restrict__ b1,
    const float* __restrict__ w2, const float* __restrict__ b2,
    const float* __restrict__ w3, const float* __restrict__ b3,
    float* __restrict__ out, float inv_nb, float inv_na)
{
    __shared__ float x[96];
    __shared__ float hs[64];
    const int t = threadIdx.x;
    if (t < 32)       x[t] = bsum[t] * inv_nb;
    else if (t < 64)  x[t] = asum[t - 32] * inv_na;
    else if (t < 96)  x[t] = state[t - 64];
    __syncthreads();
    if (t < 64) {
        float acc = b1[t];
        for (int k = 0; k < 96; ++k) acc = fmaf(x[k], w1[k * 64 + t], acc);
        hs[t] = selu_f(acc);
    }
    __syncthreads();
    float acc2 = 0.0f;
    if (t < 64) {
        acc2 = b2[t];
        for (int k = 0; k < 64; ++k) acc2 = fmaf(hs[k], w2[k * 64 + t], acc2);
        acc2 = selu_f(acc2);
    }
    __syncthreads();
    if (t < 64) hs[t] = acc2;
    __syncthreads();
    if (t < 32) {
        float acc = b3[t];
        for (int k = 0; k < 64; ++k) acc = fmaf(hs[k], w3[k * 32 + t], acc);
        out[t] = selu_f(acc);
    }
}

extern "C" void kernel_launch(void* const* d_in, const int* in_sizes, int n_in,
                              void* d_out, int out_size, void* d_ws, size_t ws_size,
                              hipStream_t stream) {
    const float* bonds = (const float*)d_in[0];
    const int*   ba1   = (const int*)d_in[1];
    const int*   ba2   = (const int*)d_in[2];
    const float* atoms = (const float*)d_in[3];
    const float* state = (const float*)d_in[4];
    const float* ew1 = (const float*)d_in[5];  const float* eb1 = (const float*)d_in[6];
    const float* ew2 = (const float*)d_in[7];  const float* eb2 = (const float*)d_in[8];
    const float* ew3 = (const float*)d_in[9];  const float* eb3 = (const float*)d_in[10];
    const float* vw1 = (const float*)d_in[11]; const float* vb1 = (const float*)d_in[12];
    const float* vw2 = (const float*)d_in[13]; const float* vb2 = (const float*)d_in[14];
    const float* vw3 = (const float*)d_in[15]; const float* vb3 = (const float*)d_in[16];
    const float* uw1 = (const float*)d_in[17]; const float* ub1 = (const float*)d_in[18];
    const float* uw2 = (const float*)d_in[19]; const float* ub2 = (const float*)d_in[20];
    const float* uw3 = (const float*)d_in[21]; const float* ub3 = (const float*)d_in[22];

    const int nb = in_sizes[1];          // 2e6
    const int na = in_sizes[3] / 32;     // 1e5

    float* out       = (float*)d_out;
    float* bonds_out = out;
    float* atoms_out = out + (size_t)nb * 32;
    float* state_out = atoms_out + (size_t)na * 32;

    // workspace layout (all 16B-aligned): b2a accum [na*32] f32, cnt [na] i32, bsum[32], asum[32]
    float* b2a  = (float*)d_ws;
    int*   cnt  = (int*)((char*)d_ws + (size_t)na * 32 * 4);
    float* bsum = (float*)((char*)d_ws + (size_t)na * 32 * 4 + (size_t)na * 4);
    float* asum = bsum + 32;
    const size_t zero_bytes = (size_t)na * 32 * 4 + (size_t)na * 4 + 64 * 4;
    hipMemsetAsync(d_ws, 0, zero_bytes, stream);

    phi_e_kernel<<<4096, BLK, 0, stream>>>(bonds, ba1, ba2, atoms, state,
                                           ew1, eb1, ew2, eb2, ew3, eb3,
                                           bonds_out, b2a, cnt, bsum, nb);

    phi_v_kernel<<<(na + BLK - 1) / BLK, BLK, 0, stream>>>(atoms, state, b2a, cnt,
                                                           vw1, vb1, vw2, vb2, vw3, vb3,
                                                           atoms_out, asum, na);

    phi_u_kernel<<<1, 128, 0, stream>>>(bsum, asum, state,
                                        uw1, ub1, uw2, ub2, uw3, ub3,
                                        state_out, 1.0f / (float)nb, 1.0f / (float)na);
}

// Round 2
// 3962.869 us; speedup vs baseline: 1.4436x; 1.4436x over previous
//
#include <hip/hip_runtime.h>
#include <math.h>

#define BLK 128
#define SCAN_BLK 1024

static constexpr float SELU_SCALE = 1.0507009873554805f;
static constexpr float SELU_ALPHA = 1.6732632423543772f;

__device__ __forceinline__ float selu_f(float x) {
    return x > 0.0f ? SELU_SCALE * x : (SELU_SCALE * SELU_ALPHA) * (expf(x) - 1.0f);
}

__device__ __forceinline__ void fmac64(float (&h)[64], float x, const float* __restrict__ w) {
    #pragma unroll
    for (int j = 0; j < 64; ++j) h[j] = fmaf(x, w[j], h[j]);
}

__device__ __forceinline__ void fmac32(float (&o)[32], float x, const float* __restrict__ w) {
    #pragma unroll
    for (int j = 0; j < 32; ++j) o[j] = fmaf(x, w[j], o[j]);
}

// accumulate a 32-wide input chunk (per-lane pointer xp) into h[64]; w is the [32,64] block
__device__ __forceinline__ void chunk32_64(float (&h)[64], const float* __restrict__ xp,
                                           const float* __restrict__ w) {
    for (int k = 0; k < 32; k += 4) {
        const float4 xv = *reinterpret_cast<const float4*>(xp + k);
        fmac64(h, xv.x, w + (k + 0) * 64);
        fmac64(h, xv.y, w + (k + 1) * 64);
        fmac64(h, xv.z, w + (k + 2) * 64);
        fmac64(h, xv.w, w + (k + 3) * 64);
    }
}

// ---------- CSR build ----------

__global__ __launch_bounds__(256) void cnt_kernel(const int* __restrict__ ba1,
                                                  int* __restrict__ cnt, int nb) {
    for (int e = blockIdx.x * 256 + threadIdx.x; e < nb; e += gridDim.x * 256)
        atomicAdd(cnt + ba1[e], 1);
}

__global__ __launch_bounds__(SCAN_BLK) void scan_block_kernel(const int* __restrict__ cnt,
                                                              int* __restrict__ excl,
                                                              int* __restrict__ bsums, int na) {
    __shared__ int tmp[SCAN_BLK];
    const int t = threadIdx.x;
    const int base = blockIdx.x * SCAN_BLK;
    const int v = (base + t < na) ? cnt[base + t] : 0;
    tmp[t] = v;
    __syncthreads();
    for (int off = 1; off < SCAN_BLK; off <<= 1) {
        const int add = (t >= off) ? tmp[t - off] : 0;
        __syncthreads();
        tmp[t] += add;
        __syncthreads();
    }
    if (base + t < na) excl[base + t] = tmp[t] - v;   // exclusive within block
    if (t == SCAN_BLK - 1) bsums[blockIdx.x] = tmp[t];
}

__global__ void scan_tops_kernel(const int* __restrict__ bsums, int* __restrict__ bases,
                                 int nblocks) {
    if (threadIdx.x == 0 && blockIdx.x == 0) {
        int s = 0;
        for (int b = 0; b < nblocks; ++b) { bases[b] = s; s += bsums[b]; }
    }
}

__global__ __launch_bounds__(256) void wcur_init_kernel(const int* __restrict__ excl,
                                                        const int* __restrict__ bases,
                                                        int* __restrict__ wcur, int na) {
    const int a = blockIdx.x * 256 + threadIdx.x;
    if (a < na) wcur[a] = bases[a >> 10] + excl[a];
}

__global__ __launch_bounds__(256) void fill_kernel(const int* __restrict__ ba1,
                                                   int* __restrict__ wcur,
                                                   int* __restrict__ list, int nb) {
    for (int e = blockIdx.x * 256 + threadIdx.x; e < nb; e += gridDim.x * 256) {
        const int pos = atomicAdd(wcur + ba1[e], 1);
        list[pos] = e;
    }
}

// fold the loop-invariant state @ W1 chunk into an effective layer-1 bias
__global__ void bias_prep_kernel(const float* __restrict__ state,
                                 const float* __restrict__ ew1, const float* __restrict__ eb1,
                                 const float* __restrict__ vw1, const float* __restrict__ vb1,
                                 float* __restrict__ ebias, float* __restrict__ vbias) {
    const int t = threadIdx.x;   // 64 threads, 2 blocks
    if (t >= 64) return;
    if (blockIdx.x == 0) {
        float acc = eb1[t];
        for (int k = 0; k < 32; ++k) acc = fmaf(state[k], ew1[(96 + k) * 64 + t], acc);
        ebias[t] = acc;
    } else {
        float acc = vb1[t];
        for (int k = 0; k < 32; ++k) acc = fmaf(state[k], vw1[(64 + k) * 64 + t], acc);
        vbias[t] = acc;
    }
}

// ---------- phi_e: edge MLP, no scatter ----------

__global__ __launch_bounds__(BLK) void phi_e_kernel(
    const float* __restrict__ bonds, const int* __restrict__ ba1, const int* __restrict__ ba2,
    const float* __restrict__ atoms,
    const float* __restrict__ w1, const float* __restrict__ ebias,
    const float* __restrict__ w2, const float* __restrict__ b2,
    const float* __restrict__ w3, const float* __restrict__ b3,
    float* __restrict__ out, float* __restrict__ bsum, int nb)
{
    __shared__ float hbuf[64][BLK];   // per-thread column: no cross-thread sharing, no barriers
    const int tid = threadIdx.x;
    float ssum[32];
    #pragma unroll
    for (int j = 0; j < 32; ++j) ssum[j] = 0.0f;

    for (int e = blockIdx.x * BLK + tid; e < nb; e += gridDim.x * BLK) {
        const int i1 = ba1[e];
        const int i2 = ba2[e];

        float h[64];
        #pragma unroll
        for (int j = 0; j < 64; ++j) h[j] = ebias[j];
        chunk32_64(h, atoms + (size_t)i1 * 32, w1);             // a1
        chunk32_64(h, atoms + (size_t)i2 * 32, w1 + 32 * 64);   // a2
        chunk32_64(h, bonds + (size_t)e * 32,  w1 + 64 * 64);   // bond
        #pragma unroll
        for (int j = 0; j < 64; ++j) hbuf[j][tid] = selu_f(h[j]);

        // layer 2: 64 -> 64
        #pragma unroll
        for (int j = 0; j < 64; ++j) h[j] = b2[j];
        for (int k = 0; k < 64; k += 4) {
            const float x0 = hbuf[k + 0][tid], x1 = hbuf[k + 1][tid];
            const float x2 = hbuf[k + 2][tid], x3 = hbuf[k + 3][tid];
            fmac64(h, x0, w2 + (k + 0) * 64);
            fmac64(h, x1, w2 + (k + 1) * 64);
            fmac64(h, x2, w2 + (k + 2) * 64);
            fmac64(h, x3, w2 + (k + 3) * 64);
        }
        #pragma unroll
        for (int j = 0; j < 64; ++j) hbuf[j][tid] = selu_f(h[j]);

        // layer 3: 64 -> 32
        float o[32];
        #pragma unroll
        for (int j = 0; j < 32; ++j) o[j] = b3[j];
        for (int k = 0; k < 64; k += 4) {
            const float x0 = hbuf[k + 0][tid], x1 = hbuf[k + 1][tid];
            const float x2 = hbuf[k + 2][tid], x3 = hbuf[k + 3][tid];
            fmac32(o, x0, w3 + (k + 0) * 32);
            fmac32(o, x1, w3 + (k + 1) * 32);
            fmac32(o, x2, w3 + (k + 2) * 32);
            fmac32(o, x3, w3 + (k + 3) * 32);
        }
        #pragma unroll
        for (int j = 0; j < 32; ++j) o[j] = selu_f(o[j]);

        float* __restrict__ op = out + (size_t)e * 32;
        #pragma unroll
        for (int j = 0; j < 32; j += 4)
            *reinterpret_cast<float4*>(op + j) = make_float4(o[j], o[j+1], o[j+2], o[j+3]);

        #pragma unroll
        for (int j = 0; j < 32; ++j) ssum[j] += o[j];
    }

    // wave-level reduce of per-thread feature sums, one atomic per wave per feature
    #pragma unroll
    for (int j = 0; j < 32; ++j) {
        float v = ssum[j];
        #pragma unroll
        for (int off = 32; off > 0; off >>= 1) v += __shfl_down(v, off);
        if ((tid & 63) == 0) atomicAdd(bsum + j, v);
    }
}

// ---------- phi_v: gather bond messages via CSR, then atom MLP ----------

__global__ __launch_bounds__(BLK) void phi_v_kernel(
    const float* __restrict__ atoms,
    const float* __restrict__ bonds_new, const int* __restrict__ list,
    const int* __restrict__ excl, const int* __restrict__ bases, const int* __restrict__ cnt,
    const float* __restrict__ w1, const float* __restrict__ vbias,
    const float* __restrict__ w2, const float* __restrict__ b2,
    const float* __restrict__ w3, const float* __restrict__ b3,
    float* __restrict__ out, float* __restrict__ asum, int na)
{
    __shared__ float hbuf[64][BLK];
    const int tid = threadIdx.x;
    float ssum[32];
    #pragma unroll
    for (int j = 0; j < 32; ++j) ssum[j] = 0.0f;

    for (int a = blockIdx.x * BLK + tid; a < na; a += gridDim.x * BLK) {
        const int start = bases[a >> 10] + excl[a];
        const int n = cnt[a];
        const float cntf = (float)n;

        float acc[32];
        #pragma unroll
        for (int j = 0; j < 32; ++j) acc[j] = 0.0f;
        for (int p = start; p < start + n; ++p) {
            const int e = list[p];
            const float* __restrict__ r = bonds_new + (size_t)e * 32;
            #pragma unroll
            for (int j = 0; j < 32; j += 4) {
                const float4 rv = *reinterpret_cast<const float4*>(r + j);
                acc[j + 0] += rv.x; acc[j + 1] += rv.y;
                acc[j + 2] += rv.z; acc[j + 3] += rv.w;
            }
        }
        #pragma unroll
        for (int j = 0; j < 32; ++j) acc[j] = acc[j] / cntf;

        float h[64];
        #pragma unroll
        for (int j = 0; j < 64; ++j) h[j] = vbias[j];
        #pragma unroll
        for (int k = 0; k < 32; ++k) fmac64(h, acc[k], w1 + k * 64);
        chunk32_64(h, atoms + (size_t)a * 32, w1 + 32 * 64);
        #pragma unroll
        for (int j = 0; j < 64; ++j) hbuf[j][tid] = selu_f(h[j]);

        #pragma unroll
        for (int j = 0; j < 64; ++j) h[j] = b2[j];
        for (int k = 0; k < 64; k += 4) {
            const float x0 = hbuf[k + 0][tid], x1 = hbuf[k + 1][tid];
            const float x2 = hbuf[k + 2][tid], x3 = hbuf[k + 3][tid];
            fmac64(h, x0, w2 + (k + 0) * 64);
            fmac64(h, x1, w2 + (k + 1) * 64);
            fmac64(h, x2, w2 + (k + 2) * 64);
            fmac64(h, x3, w2 + (k + 3) * 64);
        }
        #pragma unroll
        for (int j = 0; j < 64; ++j) hbuf[j][tid] = selu_f(h[j]);

        float o[32];
        #pragma unroll
        for (int j = 0; j < 32; ++j) o[j] = b3[j];
        for (int k = 0; k < 64; k += 4) {
            const float x0 = hbuf[k + 0][tid], x1 = hbuf[k + 1][tid];
            const float x2 = hbuf[k + 2][tid], x3 = hbuf[k + 3][tid];
            fmac32(o, x0, w3 + (k + 0) * 32);
            fmac32(o, x1, w3 + (k + 1) * 32);
            fmac32(o, x2, w3 + (k + 2) * 32);
            fmac32(o, x3, w3 + (k + 3) * 32);
        }
        #pragma unroll
        for (int j = 0; j < 32; ++j) o[j] = selu_f(o[j]);

        float* __restrict__ op = out + (size_t)a * 32;
        #pragma unroll
        for (int j = 0; j < 32; j += 4)
            *reinterpret_cast<float4*>(op + j) = make_float4(o[j], o[j+1], o[j+2], o[j+3]);

        #pragma unroll
        for (int j = 0; j < 32; ++j) ssum[j] += o[j];
    }

    #pragma unroll
    for (int j = 0; j < 32; ++j) {
        float v = ssum[j];
        #pragma unroll
        for (int off = 32; off > 0; off >>= 1) v += __shfl_down(v, off);
        if ((tid & 63) == 0) atomicAdd(asum + j, v);
    }
}

__global__ __launch_bounds__(128) void phi_u_kernel(
    const float* __restrict__ bsum, const float* __restrict__ asum,
    const float* __restrict__ state,
    const float* __restrict__ w1, const float* __restrict__ b1,
    const float* __restrict__ w2, const float* __restrict__ b2,
    const float* __restrict__ w3, const float* __restrict__ b3,
    float* __restrict__ out, float inv_nb, float inv_na)
{
    __shared__ float x[96];
    __shared__ float hs[64];
    const int t = threadIdx.x;
    if (t < 32)       x[t] = bsum[t] * inv_nb;
    else if (t < 64)  x[t] = asum[t - 32] * inv_na;
    else if (t < 96)  x[t] = state[t - 64];
    __syncthreads();
    if (t < 64) {
        float acc = b1[t];
        for (int k = 0; k < 96; ++k) acc = fmaf(x[k], w1[k * 64 + t], acc);
        hs[t] = selu_f(acc);
    }
    __syncthreads();
    float acc2 = 0.0f;
    if (t < 64) {
        acc2 = b2[t];
        for (int k = 0; k < 64; ++k) acc2 = fmaf(hs[k], w2[k * 64 + t], acc2);
        acc2 = selu_f(acc2);
    }
    __syncthreads();
    if (t < 64) hs[t] = acc2;
    __syncthreads();
    if (t < 32) {
        float acc = b3[t];
        for (int k = 0; k < 64; ++k) acc = fmaf(hs[k], w3[k * 32 + t], acc);
        out[t] = selu_f(acc);
    }
}

extern "C" void kernel_launch(void* const* d_in, const int* in_sizes, int n_in,
                              void* d_out, int out_size, void* d_ws, size_t ws_size,
                              hipStream_t stream) {
    const float* bonds = (const float*)d_in[0];
    const int*   ba1   = (const int*)d_in[1];
    const int*   ba2   = (const int*)d_in[2];
    const float* atoms = (const float*)d_in[3];
    const float* state = (const float*)d_in[4];
    const float* ew1 = (const float*)d_in[5];  const float* eb1 = (const float*)d_in[6];
    const float* ew2 = (const float*)d_in[7];  const float* eb2 = (const float*)d_in[8];
    const float* ew3 = (const float*)d_in[9];  const float* eb3 = (const float*)d_in[10];
    const float* vw1 = (const float*)d_in[11]; const float* vb1 = (const float*)d_in[12];
    const float* vw2 = (const float*)d_in[13]; const float* vb2 = (const float*)d_in[14];
    const float* vw3 = (const float*)d_in[15]; const float* vb3 = (const float*)d_in[16];
    const float* uw1 = (const float*)d_in[17]; const float* ub1 = (const float*)d_in[18];
    const float* uw2 = (const float*)d_in[19]; const float* ub2 = (const float*)d_in[20];
    const float* uw3 = (const float*)d_in[21]; const float* ub3 = (const float*)d_in[22];

    const int nb = in_sizes[1];          // 2e6
    const int na = in_sizes[3] / 32;     // 1e5
    const int nscan = (na + SCAN_BLK - 1) / SCAN_BLK;   // 98

    float* out       = (float*)d_out;
    float* bonds_out = out;
    float* atoms_out = out + (size_t)nb * 32;
    float* state_out = atoms_out + (size_t)na * 32;

    // ---- workspace layout (all offsets 16B-aligned) ----
    char* ws = (char*)d_ws;
    size_t off = 0;
    int*   cnt   = (int*)(ws + off);   off += (size_t)na * 4;        // zeroed
    float* bsum  = (float*)(ws + off); off += 32 * 4;                // zeroed
    float* asum  = (float*)(ws + off); off += 32 * 4;                // zeroed
    const size_t zero_bytes = off;
    float* ebias = (float*)(ws + off); off += 64 * 4;
    float* vbias = (float*)(ws + off); off += 64 * 4;
    int*   excl  = (int*)(ws + off);   off += (size_t)na * 4;
    int*   bsums = (int*)(ws + off);   off += 512;
    int*   bases = (int*)(ws + off);   off += 512;
    int*   wcur  = (int*)(ws + off);   off += (size_t)na * 4;
    int*   list  = (int*)(ws + off);   off += (size_t)nb * 4;

    hipMemsetAsync(d_ws, 0, zero_bytes, stream);

    bias_prep_kernel<<<2, 64, 0, stream>>>(state, ew1, eb1, vw1, vb1, ebias, vbias);

    // CSR build: count -> scan -> fill
    cnt_kernel<<<2048, 256, 0, stream>>>(ba1, cnt, nb);
    scan_block_kernel<<<nscan, SCAN_BLK, 0, stream>>>(cnt, excl, bsums, na);
    scan_tops_kernel<<<1, 64, 0, stream>>>(bsums, bases, nscan);
    wcur_init_kernel<<<(na + 255) / 256, 256, 0, stream>>>(excl, bases, wcur, na);
    fill_kernel<<<2048, 256, 0, stream>>>(ba1, wcur, list, nb);

    phi_e_kernel<<<4096, BLK, 0, stream>>>(bonds, ba1, ba2, atoms,
                                           ew1, ebias, ew2, eb2, ew3, eb3,
                                           bonds_out, bsum, nb);

    phi_v_kernel<<<(na + BLK - 1) / BLK, BLK, 0, stream>>>(atoms, bonds_out, list,
                                                           excl, bases, cnt,
                                                           vw1, vbias, vw2, vb2, vw3, vb3,
                                                           atoms_out, asum, na);

    phi_u_kernel<<<1, 128, 0, stream>>>(bsum, asum, state,
                                        uw1, ub1, uw2, ub2, uw3, ub3,
                                        state_out, 1.0f / (float)nb, 1.0f / (float)na);
}

// Round 5
// 1199.982 us; speedup vs baseline: 4.7674x; 3.3024x over previous
//
#include <hip/hip_runtime.h>
#include <math.h>

typedef __attribute__((ext_vector_type(4))) int    int4v;
typedef __attribute__((ext_vector_type(4))) float  float4v;
typedef __attribute__((ext_vector_type(8))) __bf16 bf16x8;

#define SCAN_BLK 1024

static constexpr float SELU_SCALE = 1.0507009873554805f;
static constexpr float SELU_ALPHA = 1.6732632423543772f;

__device__ __forceinline__ float selu_f(float x) {
    const float sa = SELU_SCALE * SELU_ALPHA;
    float e = __expf(x);
    return x > 0.0f ? SELU_SCALE * x : fmaf(sa, e, -sa);
}

__device__ __forceinline__ unsigned short f2bf(float f) {
    uint32_t u = __builtin_bit_cast(uint32_t, f);
    return (unsigned short)((u + 0x7FFFu + ((u >> 16) & 1u)) >> 16);
}

// pack two floats to bf16x2: a -> bits[15:0], b -> bits[31:16]
__device__ __forceinline__ uint32_t pk2(float a, float b) {
    return (uint32_t)f2bf(a) | ((uint32_t)f2bf(b) << 16);
}

// builtin MFMA: compiler knows the semantics -> correct hazard nops + scheduling.
__device__ __forceinline__ float4v mfma_bf16(int4v a, int4v b, float4v c) {
    return __builtin_amdgcn_mfma_f32_16x16x32_bf16(
        __builtin_bit_cast(bf16x8, a), __builtin_bit_cast(bf16x8, b), c, 0, 0, 0);
}

// ---------------- CSR build ----------------

__global__ __launch_bounds__(256) void cnt_kernel(const int* __restrict__ ba1,
                                                  int* __restrict__ cnt, int nb) {
    for (int e = blockIdx.x * 256 + threadIdx.x; e < nb; e += gridDim.x * 256)
        atomicAdd(cnt + ba1[e], 1);
}

__global__ __launch_bounds__(SCAN_BLK) void scan_block_kernel(const int* __restrict__ cnt,
                                                              int* __restrict__ excl,
                                                              int* __restrict__ bsums, int na) {
    __shared__ int tmp[SCAN_BLK];
    const int t = threadIdx.x;
    const int base = blockIdx.x * SCAN_BLK;
    const int v = (base + t < na) ? cnt[base + t] : 0;
    tmp[t] = v;
    __syncthreads();
    for (int off = 1; off < SCAN_BLK; off <<= 1) {
        const int add = (t >= off) ? tmp[t - off] : 0;
        __syncthreads();
        tmp[t] += add;
        __syncthreads();
    }
    if (base + t < na) excl[base + t] = tmp[t] - v;
    if (t == SCAN_BLK - 1) bsums[blockIdx.x] = tmp[t];
}

__global__ void scan_tops_kernel(const int* __restrict__ bsums, int* __restrict__ bases,
                                 int nblocks) {
    if (threadIdx.x == 0 && blockIdx.x == 0) {
        int s = 0;
        for (int bk = 0; bk < nblocks; ++bk) { bases[bk] = s; s += bsums[bk]; }
    }
}

__global__ __launch_bounds__(256) void wcur_init_kernel(const int* __restrict__ excl,
                                                        const int* __restrict__ bases,
                                                        int* __restrict__ wcur, int na) {
    const int a = blockIdx.x * 256 + threadIdx.x;
    if (a < na) wcur[a] = bases[a >> 10] + excl[a];
}

__global__ __launch_bounds__(256) void fill_kernel(const int* __restrict__ ba1,
                                                   int* __restrict__ wcur,
                                                   int* __restrict__ list, int nb) {
    for (int e = blockIdx.x * 256 + threadIdx.x; e < nb; e += gridDim.x * 256) {
        const int pos = atomicAdd(wcur + ba1[e], 1);
        list[pos] = e;
    }
}

// ---------------- prep: fold state into layer-1 bias ----------------

__global__ void bias_prep_kernel(const float* __restrict__ state,
                                 const float* __restrict__ ew1, const float* __restrict__ eb1,
                                 const float* __restrict__ vw1, const float* __restrict__ vb1,
                                 float* __restrict__ ebias, float* __restrict__ vbias) {
    const int t = threadIdx.x;
    if (t >= 64) return;
    if (blockIdx.x == 0) {
        float acc = eb1[t];
        for (int k = 0; k < 32; ++k) acc = fmaf(state[k], ew1[(96 + k) * 64 + t], acc);
        ebias[t] = acc;
    } else {
        float acc = vb1[t];
        for (int k = 0; k < 32; ++k) acc = fmaf(state[k], vw1[(64 + k) * 64 + t], acc);
        vbias[t] = acc;
    }
}

// ---------------- prep: weights -> bf16 MFMA A-fragments ----------------
// Fragment fid layout (each 64 lanes x 8 bf16 = 512 ushorts):
//   e: L1 fid=t*3+c (t<4,c<3), L2 fid=12+t*2+c, L3 fid=20+t*2+c (t<2)
//   v: L1 fid=24+t*2+c, L2 fid=32+t*2+c, L3 fid=40+t*2+c (t<2)
// value(lane,j) = W[32c + 8g + j][16t + b],  b=lane&15, g=lane>>4
__global__ __launch_bounds__(256) void wprep_kernel(
    const float* __restrict__ ew1, const float* __restrict__ ew2, const float* __restrict__ ew3,
    const float* __restrict__ vw1, const float* __restrict__ vw2, const float* __restrict__ vw3,
    unsigned short* __restrict__ wfe, unsigned short* __restrict__ wfv)
{
    const int idx = blockIdx.x * 256 + threadIdx.x;
    if (idx >= 44 * 64) return;
    const int fid = idx >> 6, lane = idx & 63;
    const int b = lane & 15, g = lane >> 4;
    const float* W; int N, t, c;
    if (fid < 12)      { W = ew1; N = 64; t = fid / 3;        c = fid % 3; }
    else if (fid < 20) { W = ew2; N = 64; t = (fid - 12) / 2; c = (fid - 12) % 2; }
    else if (fid < 24) { W = ew3; N = 32; t = (fid - 20) / 2; c = (fid - 20) % 2; }
    else if (fid < 32) { W = vw1; N = 64; t = (fid - 24) / 2; c = (fid - 24) % 2; }
    else if (fid < 40) { W = vw2; N = 64; t = (fid - 32) / 2; c = (fid - 32) % 2; }
    else               { W = vw3; N = 32; t = (fid - 40) / 2; c = (fid - 40) % 2; }
    unsigned short* dst = (fid < 24) ? (wfe + fid * 512) : (wfv + (fid - 24) * 512);
    for (int j = 0; j < 8; ++j) {
        const float w = W[(size_t)(32 * c + 8 * g + j) * N + 16 * t + b];
        dst[lane * 8 + j] = f2bf(w);
    }
}

// ---------------- phi_e: MFMA edge MLP ----------------
// Per wave: 16 bonds. Swapped operands: D[n'][bond] = W^T-tile x x^T-tile.
// D layout: bond = lane&15, n = 16t + 4g + i (HW-verified C/D mapping).

__global__ __launch_bounds__(256) void phi_e_mfma(
    const float* __restrict__ bonds, const int* __restrict__ ba1, const int* __restrict__ ba2,
    const float* __restrict__ atoms,
    const unsigned short* __restrict__ wfe, const float* __restrict__ ebias,
    const float* __restrict__ eb2, const float* __restrict__ eb3,
    float* __restrict__ out, float* __restrict__ bsum, int nb)
{
    __shared__ __align__(16) char lds_raw[4 * 2048];
    const int tid = threadIdx.x;
    const int wid = tid >> 6, lane = tid & 63;
    const int b = lane & 15, g = lane >> 4;
    char* hb = lds_raw + wid * 2048;                 // private per-wave strip, no barriers
    const uint32_t swz = (uint32_t)((b & 7) << 4);   // XOR-swizzle vs 128B-row bank conflicts
    const uint32_t row = (uint32_t)(b * 128);

    int4v we1[4][3], we2[4][2], we3[2][2];
    #pragma unroll
    for (int t = 0; t < 4; ++t)
        #pragma unroll
        for (int c = 0; c < 3; ++c)
            we1[t][c] = *(const int4v*)(wfe + (t * 3 + c) * 512 + lane * 8);
    #pragma unroll
    for (int t = 0; t < 4; ++t)
        #pragma unroll
        for (int c = 0; c < 2; ++c)
            we2[t][c] = *(const int4v*)(wfe + (12 + t * 2 + c) * 512 + lane * 8);
    #pragma unroll
    for (int t = 0; t < 2; ++t)
        #pragma unroll
        for (int c = 0; c < 2; ++c)
            we3[t][c] = *(const int4v*)(wfe + (20 + t * 2 + c) * 512 + lane * 8);

    float ssum[8];
    #pragma unroll
    for (int i = 0; i < 8; ++i) ssum[i] = 0.0f;

    const int ntile = (nb + 15) >> 4;
    for (int m = blockIdx.x * 4 + wid; m < ntile; m += gridDim.x * 4) {
        const int e0 = m << 4;
        const int er = (e0 + b < nb) ? (e0 + b) : (nb - 1);
        const int i1 = ba1[er], i2 = ba2[er];

        int4v xa1, xa2, xb;
        {
            const float* p = atoms + (size_t)i1 * 32 + 8 * g;
            const float4 u0 = *(const float4*)p, u1 = *(const float4*)(p + 4);
            xa1[0] = (int)pk2(u0.x, u0.y); xa1[1] = (int)pk2(u0.z, u0.w);
            xa1[2] = (int)pk2(u1.x, u1.y); xa1[3] = (int)pk2(u1.z, u1.w);
        }
        {
            const float* p = atoms + (size_t)i2 * 32 + 8 * g;
            const float4 u0 = *(const float4*)p, u1 = *(const float4*)(p + 4);
            xa2[0] = (int)pk2(u0.x, u0.y); xa2[1] = (int)pk2(u0.z, u0.w);
            xa2[2] = (int)pk2(u1.x, u1.y); xa2[3] = (int)pk2(u1.z, u1.w);
        }
        {
            const float* p = bonds + (size_t)er * 32 + 8 * g;
            const float4 u0 = *(const float4*)p, u1 = *(const float4*)(p + 4);
            xb[0] = (int)pk2(u0.x, u0.y); xb[1] = (int)pk2(u0.z, u0.w);
            xb[2] = (int)pk2(u1.x, u1.y); xb[3] = (int)pk2(u1.z, u1.w);
        }

        // layer 1: K=96 (3 chunks), N=64 (4 tiles)
        float4v acc[4];
        #pragma unroll
        for (int t = 0; t < 4; ++t) acc[t] = *(const float4v*)(ebias + 16 * t + 4 * g);
        #pragma unroll
        for (int t = 0; t < 4; ++t) {
            acc[t] = mfma_bf16(we1[t][0], xa1, acc[t]);
            acc[t] = mfma_bf16(we1[t][1], xa2, acc[t]);
            acc[t] = mfma_bf16(we1[t][2], xb,  acc[t]);
        }
        #pragma unroll
        for (int t = 0; t < 4; ++t) {
            const float s0 = selu_f(acc[t][0]), s1 = selu_f(acc[t][1]);
            const float s2 = selu_f(acc[t][2]), s3 = selu_f(acc[t][3]);
            const uint32_t q = (uint32_t)(t * 32 + g * 8);
            *(uint2*)(hb + row + (q ^ swz)) = make_uint2(pk2(s0, s1), pk2(s2, s3));
        }
        int4v xh0 = *(const int4v*)(hb + row + (((uint32_t)(g * 16)) ^ swz));
        int4v xh1 = *(const int4v*)(hb + row + (((uint32_t)(64 + g * 16)) ^ swz));

        // layer 2: K=64 (2 chunks), N=64
        #pragma unroll
        for (int t = 0; t < 4; ++t) acc[t] = *(const float4v*)(eb2 + 16 * t + 4 * g);
        #pragma unroll
        for (int t = 0; t < 4; ++t) {
            acc[t] = mfma_bf16(we2[t][0], xh0, acc[t]);
            acc[t] = mfma_bf16(we2[t][1], xh1, acc[t]);
        }
        #pragma unroll
        for (int t = 0; t < 4; ++t) {
            const float s0 = selu_f(acc[t][0]), s1 = selu_f(acc[t][1]);
            const float s2 = selu_f(acc[t][2]), s3 = selu_f(acc[t][3]);
            const uint32_t q = (uint32_t)(t * 32 + g * 8);
            *(uint2*)(hb + row + (q ^ swz)) = make_uint2(pk2(s0, s1), pk2(s2, s3));
        }
        xh0 = *(const int4v*)(hb + row + (((uint32_t)(g * 16)) ^ swz));
        xh1 = *(const int4v*)(hb + row + (((uint32_t)(64 + g * 16)) ^ swz));

        // layer 3: K=64, N=32 (2 tiles)
        float4v acc3[2];
        acc3[0] = *(const float4v*)(eb3 + 4 * g);
        acc3[1] = *(const float4v*)(eb3 + 16 + 4 * g);
        #pragma unroll
        for (int t = 0; t < 2; ++t) {
            acc3[t] = mfma_bf16(we3[t][0], xh0, acc3[t]);
            acc3[t] = mfma_bf16(we3[t][1], xh1, acc3[t]);
        }
        if (e0 + b < nb) {
            #pragma unroll
            for (int t = 0; t < 2; ++t) {
                const float o0 = selu_f(acc3[t][0]), o1 = selu_f(acc3[t][1]);
                const float o2 = selu_f(acc3[t][2]), o3 = selu_f(acc3[t][3]);
                *(float4*)(out + (size_t)(e0 + b) * 32 + 16 * t + 4 * g) =
                    make_float4(o0, o1, o2, o3);
                ssum[t * 4 + 0] += o0; ssum[t * 4 + 1] += o1;
                ssum[t * 4 + 2] += o2; ssum[t * 4 + 3] += o3;
            }
        }
    }

    // reduce ssum over the 16 b-lanes of each g-group; feature n = 16*(i>>2)+4g+(i&3)
    #pragma unroll
    for (int i = 0; i < 8; ++i) {
        float v = ssum[i];
        v += __shfl_xor(v, 1); v += __shfl_xor(v, 2);
        v += __shfl_xor(v, 4); v += __shfl_xor(v, 8);
        if (b == 0) atomicAdd(bsum + 16 * (i >> 2) + 4 * g + (i & 3), v);
    }
}

// ---------------- gather: per-atom mean of bond messages -> mean[a][32] ----------------
// 8 threads per atom, one float4 column-chunk each.

__global__ __launch_bounds__(256) void gather_mean_kernel(
    const float* __restrict__ bonds_new, const int* __restrict__ list,
    const int* __restrict__ excl, const int* __restrict__ bases,
    const int* __restrict__ cnt, float* __restrict__ mean, int na)
{
    const int idx = blockIdx.x * 256 + threadIdx.x;
    const int a = idx >> 3, q = idx & 7;
    if (a >= na) return;
    const int start = bases[a >> 10] + excl[a];
    const int n = cnt[a];
    float4 s = make_float4(0.f, 0.f, 0.f, 0.f);
    for (int p = start; p < start + n; ++p) {
        const float4 r = *(const float4*)(bonds_new + (size_t)list[p] * 32 + q * 4);
        s.x += r.x; s.y += r.y; s.z += r.z; s.w += r.w;
    }
    const float inv = 1.0f / (float)n;   // n==0 -> inf -> NaN, matching reference 0/0
    *(float4*)(mean + (size_t)a * 32 + q * 4) =
        make_float4(s.x * inv, s.y * inv, s.z * inv, s.w * inv);
}

// ---------------- phi_v: MFMA atom MLP (K=64: mean, atoms) ----------------
// mean lives in the atoms_out region; each wave reads its rows before overwriting them.

__global__ __launch_bounds__(256) void phi_v_mfma(
    const float* __restrict__ atoms, float* __restrict__ out /* = mean in, atoms_new out */,
    const unsigned short* __restrict__ wfv, const float* __restrict__ vbias,
    const float* __restrict__ vb2, const float* __restrict__ vb3,
    float* __restrict__ asum, int na)
{
    __shared__ __align__(16) char lds_raw[4 * 2048];
    const int tid = threadIdx.x;
    const int wid = tid >> 6, lane = tid & 63;
    const int b = lane & 15, g = lane >> 4;
    char* hb = lds_raw + wid * 2048;
    const uint32_t swz = (uint32_t)((b & 7) << 4);
    const uint32_t row = (uint32_t)(b * 128);

    int4v wv1[4][2], wv2[4][2], wv3[2][2];
    #pragma unroll
    for (int t = 0; t < 4; ++t)
        #pragma unroll
        for (int c = 0; c < 2; ++c) {
            wv1[t][c] = *(const int4v*)(wfv + (t * 2 + c) * 512 + lane * 8);
            wv2[t][c] = *(const int4v*)(wfv + (8 + t * 2 + c) * 512 + lane * 8);
        }
    #pragma unroll
    for (int t = 0; t < 2; ++t)
        #pragma unroll
        for (int c = 0; c < 2; ++c)
            wv3[t][c] = *(const int4v*)(wfv + (16 + t * 2 + c) * 512 + lane * 8);

    float ssum[8];
    #pragma unroll
    for (int i = 0; i < 8; ++i) ssum[i] = 0.0f;

    const int ntile = (na + 15) >> 4;
    const int m = blockIdx.x * 4 + wid;
    if (m < ntile) {
        const int a0 = m << 4;
        const int ar = (a0 + b < na) ? (a0 + b) : (na - 1);

        int4v xm, xa;
        {
            const float* p = out + (size_t)ar * 32 + 8 * g;   // mean
            const float4 u0 = *(const float4*)p, u1 = *(const float4*)(p + 4);
            xm[0] = (int)pk2(u0.x, u0.y); xm[1] = (int)pk2(u0.z, u0.w);
            xm[2] = (int)pk2(u1.x, u1.y); xm[3] = (int)pk2(u1.z, u1.w);
        }
        {
            const float* p = atoms + (size_t)ar * 32 + 8 * g;
            const float4 u0 = *(const float4*)p, u1 = *(const float4*)(p + 4);
            xa[0] = (int)pk2(u0.x, u0.y); xa[1] = (int)pk2(u0.z, u0.w);
            xa[2] = (int)pk2(u1.x, u1.y); xa[3] = (int)pk2(u1.z, u1.w);
        }

        float4v acc[4];
        #pragma unroll
        for (int t = 0; t < 4; ++t) acc[t] = *(const float4v*)(vbias + 16 * t + 4 * g);
        #pragma unroll
        for (int t = 0; t < 4; ++t) {
            acc[t] = mfma_bf16(wv1[t][0], xm, acc[t]);
            acc[t] = mfma_bf16(wv1[t][1], xa, acc[t]);
        }
        #pragma unroll
        for (int t = 0; t < 4; ++t) {
            const float s0 = selu_f(acc[t][0]), s1 = selu_f(acc[t][1]);
            const float s2 = selu_f(acc[t][2]), s3 = selu_f(acc[t][3]);
            const uint32_t q = (uint32_t)(t * 32 + g * 8);
            *(uint2*)(hb + row + (q ^ swz)) = make_uint2(pk2(s0, s1), pk2(s2, s3));
        }
        int4v xh0 = *(const int4v*)(hb + row + (((uint32_t)(g * 16)) ^ swz));
        int4v xh1 = *(const int4v*)(hb + row + (((uint32_t)(64 + g * 16)) ^ swz));

        #pragma unroll
        for (int t = 0; t < 4; ++t) acc[t] = *(const float4v*)(vb2 + 16 * t + 4 * g);
        #pragma unroll
        for (int t = 0; t < 4; ++t) {
            acc[t] = mfma_bf16(wv2[t][0], xh0, acc[t]);
            acc[t] = mfma_bf16(wv2[t][1], xh1, acc[t]);
        }
        #pragma unroll
        for (int t = 0; t < 4; ++t) {
            const float s0 = selu_f(acc[t][0]), s1 = selu_f(acc[t][1]);
            const float s2 = selu_f(acc[t][2]), s3 = selu_f(acc[t][3]);
            const uint32_t q = (uint32_t)(t * 32 + g * 8);
            *(uint2*)(hb + row + (q ^ swz)) = make_uint2(pk2(s0, s1), pk2(s2, s3));
        }
        xh0 = *(const int4v*)(hb + row + (((uint32_t)(g * 16)) ^ swz));
        xh1 = *(const int4v*)(hb + row + (((uint32_t)(64 + g * 16)) ^ swz));

        float4v acc3[2];
        acc3[0] = *(const float4v*)(vb3 + 4 * g);
        acc3[1] = *(const float4v*)(vb3 + 16 + 4 * g);
        #pragma unroll
        for (int t = 0; t < 2; ++t) {
            acc3[t] = mfma_bf16(wv3[t][0], xh0, acc3[t]);
            acc3[t] = mfma_bf16(wv3[t][1], xh1, acc3[t]);
        }
        if (a0 + b < na) {
            #pragma unroll
            for (int t = 0; t < 2; ++t) {
                const float o0 = selu_f(acc3[t][0]), o1 = selu_f(acc3[t][1]);
                const float o2 = selu_f(acc3[t][2]), o3 = selu_f(acc3[t][3]);
                *(float4*)(out + (size_t)(a0 + b) * 32 + 16 * t + 4 * g) =
                    make_float4(o0, o1, o2, o3);
                ssum[t * 4 + 0] += o0; ssum[t * 4 + 1] += o1;
                ssum[t * 4 + 2] += o2; ssum[t * 4 + 3] += o3;
            }
        }
    }

    #pragma unroll
    for (int i = 0; i < 8; ++i) {
        float v = ssum[i];
        v += __shfl_xor(v, 1); v += __shfl_xor(v, 2);
        v += __shfl_xor(v, 4); v += __shfl_xor(v, 8);
        if (b == 0) atomicAdd(asum + 16 * (i >> 2) + 4 * g + (i & 3), v);
    }
}

// ---------------- phi_u ----------------

__global__ __launch_bounds__(128) void phi_u_kernel(
    const float* __restrict__ bsum, const float* __restrict__ asum,
    const float* __restrict__ state,
    const float* __restrict__ w1, const float* __restrict__ b1,
    const float* __restrict__ w2, const float* __restrict__ b2,
    const float* __restrict__ w3, const float* __restrict__ b3,
    float* __restrict__ out, float inv_nb, float inv_na)
{
    __shared__ float x[96];
    __shared__ float hs[64];
    const int t = threadIdx.x;
    if (t < 32)       x[t] = bsum[t] * inv_nb;
    else if (t < 64)  x[t] = asum[t - 32] * inv_na;
    else if (t < 96)  x[t] = state[t - 64];
    __syncthreads();
    if (t < 64) {
        float acc = b1[t];
        for (int k = 0; k < 96; ++k) acc = fmaf(x[k], w1[k * 64 + t], acc);
        hs[t] = selu_f(acc);
    }
    __syncthreads();
    float acc2 = 0.0f;
    if (t < 64) {
        acc2 = b2[t];
        for (int k = 0; k < 64; ++k) acc2 = fmaf(hs[k], w2[k * 64 + t], acc2);
        acc2 = selu_f(acc2);
    }
    __syncthreads();
    if (t < 64) hs[t] = acc2;
    __syncthreads();
    if (t < 32) {
        float acc = b3[t];
        for (int k = 0; k < 64; ++k) acc = fmaf(hs[k], w3[k * 32 + t], acc);
        out[t] = selu_f(acc);
    }
}

extern "C" void kernel_launch(void* const* d_in, const int* in_sizes, int n_in,
                              void* d_out, int out_size, void* d_ws, size_t ws_size,
                              hipStream_t stream) {
    const float* bonds = (const float*)d_in[0];
    const int*   ba1   = (const int*)d_in[1];
    const int*   ba2   = (const int*)d_in[2];
    const float* atoms = (const float*)d_in[3];
    const float* state = (const float*)d_in[4];
    const float* ew1 = (const float*)d_in[5];  const float* eb1 = (const float*)d_in[6];
    const float* ew2 = (const float*)d_in[7];  const float* eb2 = (const float*)d_in[8];
    const float* ew3 = (const float*)d_in[9];  const float* eb3 = (const float*)d_in[10];
    const float* vw1 = (const float*)d_in[11]; const float* vb1 = (const float*)d_in[12];
    const float* vw2 = (const float*)d_in[13]; const float* vb2 = (const float*)d_in[14];
    const float* vw3 = (const float*)d_in[15]; const float* vb3 = (const float*)d_in[16];
    const float* uw1 = (const float*)d_in[17]; const float* ub1 = (const float*)d_in[18];
    const float* uw2 = (const float*)d_in[19]; const float* ub2 = (const float*)d_in[20];
    const float* uw3 = (const float*)d_in[21]; const float* ub3 = (const float*)d_in[22];

    const int nb = in_sizes[1];          // 2,000,000
    const int na = in_sizes[3] / 32;     // 100,000
    const int nscan = (na + SCAN_BLK - 1) / SCAN_BLK;

    float* out       = (float*)d_out;
    float* bonds_out = out;
    float* atoms_out = out + (size_t)nb * 32;
    float* state_out = atoms_out + (size_t)na * 32;

    // ---- workspace layout (256B-aligned chunks) ----
    char* ws = (char*)d_ws;
    size_t off = 0;
    auto alloc = [&](size_t bytes) { char* p = ws + off; off += (bytes + 255) & ~(size_t)255; return p; };
    int*   cnt   = (int*)alloc((size_t)na * 4);          // zeroed
    float* bsum  = (float*)alloc(32 * 4);                // zeroed
    float* asum  = (float*)alloc(32 * 4);                // zeroed
    const size_t zero_bytes = off;
    float* ebias = (float*)alloc(64 * 4);
    float* vbias = (float*)alloc(64 * 4);
    int*   excl  = (int*)alloc((size_t)na * 4);
    int*   bsums = (int*)alloc(128 * 4);
    int*   bases = (int*)alloc(128 * 4);
    int*   wcur  = (int*)alloc((size_t)na * 4);
    int*   list  = (int*)alloc((size_t)nb * 4);
    unsigned short* wfe = (unsigned short*)alloc(24 * 512 * 2);
    unsigned short* wfv = (unsigned short*)alloc(20 * 512 * 2);

    (void)hipMemsetAsync(d_ws, 0, zero_bytes, stream);

    bias_prep_kernel<<<2, 64, 0, stream>>>(state, ew1, eb1, vw1, vb1, ebias, vbias);
    wprep_kernel<<<(44 * 64 + 255) / 256, 256, 0, stream>>>(ew1, ew2, ew3, vw1, vw2, vw3,
                                                            wfe, wfv);

    cnt_kernel<<<2048, 256, 0, stream>>>(ba1, cnt, nb);
    scan_block_kernel<<<nscan, SCAN_BLK, 0, stream>>>(cnt, excl, bsums, na);
    scan_tops_kernel<<<1, 64, 0, stream>>>(bsums, bases, nscan);
    wcur_init_kernel<<<(na + 255) / 256, 256, 0, stream>>>(excl, bases, wcur, na);
    fill_kernel<<<2048, 256, 0, stream>>>(ba1, wcur, list, nb);

    phi_e_mfma<<<2048, 256, 0, stream>>>(bonds, ba1, ba2, atoms, wfe, ebias, eb2, eb3,
                                         bonds_out, bsum, nb);

    gather_mean_kernel<<<((na * 8) + 255) / 256, 256, 0, stream>>>(bonds_out, list, excl,
                                                                   bases, cnt, atoms_out, na);

    const int ntv = (na + 15) / 16;
    phi_v_mfma<<<(ntv + 3) / 4, 256, 0, stream>>>(atoms, atoms_out, wfv, vbias, vb2, vb3,
                                                  asum, na);

    phi_u_kernel<<<1, 128, 0, stream>>>(bsum, asum, state,
                                        uw1, ub1, uw2, ub2, uw3, ub3,
                                        state_out, 1.0f / (float)nb, 1.0f / (float)na);
}